// Round 1
// 198.309 us; speedup vs baseline: 1.1259x; 1.1259x over previous
//
#include <hip/hip_runtime.h>
#include <math.h>

#define Hd 256
#define Wd 256
#define Cd 128
#define BIGV 1.0e9f

static __device__ __forceinline__ float softplus_f(float x) {
    return fmaxf(x, 0.0f) + log1pf(expf(-fabsf(x)));
}

// ---- DPP helpers (gfx9/CDNA DPP controls; old = FLT_MAX = min identity) ----
#define FMAXBITS 0x7F7FFFFF
template<int CTRL, int RM>
static __device__ __forceinline__ float dpp_mv(float x) {
    return __int_as_float(__builtin_amdgcn_update_dpp(
        FMAXBITS, __float_as_int(x), CTRL, RM, 0xF, false));
}
template<int CTRL, int RM>
static __device__ __forceinline__ float dpp_min(float x) {
    return fminf(x, dpp_mv<CTRL, RM>(x));
}
// inclusive prefix-min across 64 lanes
static __device__ __forceinline__ float wave_prefmin(float x) {
    x = dpp_min<0x111, 0xF>(x);   // row_shr:1
    x = dpp_min<0x112, 0xF>(x);   // row_shr:2
    x = dpp_min<0x114, 0xF>(x);   // row_shr:4
    x = dpp_min<0x118, 0xF>(x);   // row_shr:8
    x = dpp_min<0x142, 0xA>(x);   // row_bcast15 -> rows 1,3
    x = dpp_min<0x143, 0xC>(x);   // row_bcast31 -> rows 2,3
    return x;
}

#define TILE 16
#define HPX 18
#define PXN 324
#define SP  325
#define CHUNK 32

// ---------------------------------------------------------------------------
// Kernel 1 (R12 split): COST-ONLY per-pixel work. Staging skeleton identical
// to the proven fused kernel; keeps only norm accumulation + 8 neighbor dots.
// The heuristic (Sobel/var/abs/MLP) moved into k_main where it overlaps the
// otherwise-idle 83 us of the 4-block sweep.
// ---------------------------------------------------------------------------
__global__ __launch_bounds__(256) void k_cost(
    const float* __restrict__ feat,
    float* __restrict__ out, float* __restrict__ costP)
{
    __shared__ float stage[CHUNK * SP];
    __shared__ float normL[PXN];

    const int t  = threadIdx.x;
    const int r0 = blockIdx.y * TILE;
    const int c0 = blockIdx.x * TILE;

    const int lr = t >> 4, lc = t & 15;
    const int r = r0 + lr, c = c0 + lc;
    const int px0 = (lr + 1) * HPX + (lc + 1);

    float dotv[8];
#pragma unroll
    for (int j = 0; j < 8; ++j) dotv[j] = 0.0f;

    for (int ch0 = 0; ch0 < Cd; ch0 += CHUNK) {
        __syncthreads();
        for (int i = t; i < PXN * 8; i += 256) {
            int px = i >> 3, f4 = i & 7;
            int pr = px / HPX;
            int pc = px - pr * HPX;
            int gr = r0 - 1 + pr, gc = c0 - 1 + pc;
            float4 v = make_float4(0.f, 0.f, 0.f, 0.f);
            if ((unsigned)gr < Hd && (unsigned)gc < Wd) {
                v = *reinterpret_cast<const float4*>(
                        &feat[(((gr << 8) + gc) * Cd) + ch0 + (f4 << 2)]);
            }
            int chb = f4 << 2;
            stage[(chb + 0) * SP + px] = v.x;
            stage[(chb + 1) * SP + px] = v.y;
            stage[(chb + 2) * SP + px] = v.z;
            stage[(chb + 3) * SP + px] = v.w;
        }
        __syncthreads();
        for (int px = t; px < PXN; px += 256) {
            float s = 0.0f;
#pragma unroll
            for (int ch = 0; ch < CHUNK; ++ch) {
                float v = stage[ch * SP + px];
                s = fmaf(v, v, s);
            }
            if (ch0 == 0) normL[px] = s; else normL[px] += s;
        }
        for (int ch = 0; ch < CHUNK; ++ch) {
            const float* pl = stage + ch * SP + px0;
            float x  = pl[0];
            float n0 = pl[-HPX - 1], n1 = pl[-HPX], n2 = pl[-HPX + 1];
            float n3 = pl[-1],                      n4 = pl[1];
            float n5 = pl[HPX - 1],  n6 = pl[HPX],  n7 = pl[HPX + 1];

            dotv[0] = fmaf(x, n0, dotv[0]);
            dotv[1] = fmaf(x, n1, dotv[1]);
            dotv[2] = fmaf(x, n2, dotv[2]);
            dotv[3] = fmaf(x, n3, dotv[3]);
            dotv[4] = fmaf(x, n4, dotv[4]);
            dotv[5] = fmaf(x, n5, dotv[5]);
            dotv[6] = fmaf(x, n6, dotv[6]);
            dotv[7] = fmaf(x, n7, dotv[7]);
        }
    }
    __syncthreads();

    const int p = (r << 8) + c;
    float np = fmaxf(sqrtf(normL[px0]), 1e-12f);
    const int drr[8] = {-1,-1,-1, 0, 0, 1, 1, 1};
    const int dcc[8] = {-1, 0, 1,-1, 1,-1, 0, 1};
    const int nof[8] = {-HPX-1,-HPX,-HPX+1,-1,1,HPX-1,HPX,HPX+1};
#pragma unroll
    for (int j = 0; j < 8; ++j) {
        int nr = r + drr[j], nc = c + dcc[j];
        float cj;
        if ((unsigned)nr < Hd && (unsigned)nc < Wd) {
            float nn = fmaxf(sqrtf(normL[px0 + nof[j]]), 1e-12f);
            cj = 1.0f - dotv[j] / (np * nn);
        } else {
            cj = BIGV;
        }
        costP[(j << 16) + p] = cj;
        out[p * 10 + 1 + j]  = cj;
    }
}

// ---------------------------------------------------------------------------
// Kernel 2: per-row exclusive prefix sums of horizontal edge costs (unchanged).
// ---------------------------------------------------------------------------
__global__ __launch_bounds__(64) void k_scan(
    const float* __restrict__ costP, float* __restrict__ PR, float* __restrict__ PRm)
{
    const int r = blockIdx.x;
    const int l = threadIdx.x;
    const int base = (r << 8) + (l << 2);

    {
        const float4 c4 = *(const float4*)&costP[(4 << 16) + base];
        float a0 = c4.x, a1 = a0 + c4.y, a2 = a1 + c4.z, a3 = a2 + c4.w;
        float ta = a3;
#pragma unroll
        for (int o = 1; o < 64; o <<= 1) {
            float xa = __shfl_up(ta, o, 64);
            if (l >= o) ta += xa;
        }
        float ea = __shfl_up(ta, 1, 64); if (l == 0) ea = 0.0f;
        float4 P; P.x = ea; P.y = ea + a0; P.z = ea + a1; P.w = ea + a2;
        *(float4*)&PR[base] = P;
    }
    {
        const float4 m = *(const float4*)&costP[(3 << 16) + (r << 8) + (252 - (l << 2))];
        float w0 = m.w, w1_ = m.z, w2_ = m.y, w3 = m.x;
        float a0 = w0, a1 = a0 + w1_, a2 = a1 + w2_, a3 = a2 + w3;
        float ta = a3;
#pragma unroll
        for (int o = 1; o < 64; o <<= 1) {
            float xa = __shfl_up(ta, o, 64);
            if (l >= o) ta += xa;
        }
        float ea = __shfl_up(ta, 1, 64); if (l == 0) ea = 0.0f;
        float4 P; P.x = ea; P.y = ea + a0; P.z = ea + a1; P.w = ea + a2;
        *(float4*)&PRm[base] = P;
    }
}

// ---------------------------------------------------------------------------
// Kernel 3 (R12 fused): blocks 0..3 = the proven quadrant sweeps (1 wave
// each, serial 256-row DP); blocks 4..259 = the heuristic (Sobel/var/abs/MLP)
// which has NO data dependency on the sweep and runs on the 252 CUs the sweep
// leaves idle. Worst-case (adverse dispatch order) the two halves serialize,
// which equals the old schedule; best case the heuristic is fully hidden.
// ---------------------------------------------------------------------------
#define PIPE 8

static __device__ __forceinline__ float4 ld4m(const float* p, int r, int l, int M) {
    if (!M) return *(const float4*)&p[(r << 8) + (l << 2)];
    float4 v = *(const float4*)&p[(r << 8) + (252 - (l << 2))];
    return make_float4(v.w, v.z, v.y, v.x);
}

__global__ __launch_bounds__(256) void k_main(
    const float* __restrict__ feat,
    const float* __restrict__ w1, const float* __restrict__ b1,
    const float* __restrict__ w2, const float* __restrict__ b2,
    const float* __restrict__ dlt, const float* __restrict__ gmm,
    const float* __restrict__ bta, const int* __restrict__ endn,
    const float* __restrict__ costP, const float* __restrict__ PR,
    const float* __restrict__ PRm, const int* __restrict__ startn,
    float* __restrict__ out, float* __restrict__ distQ)
{
    if (blockIdx.x < 4) {
        // ================= SWEEP PATH (verbatim from proven k_sweep) =======
        const int l = threadIdx.x;
        if (l >= 64) return;
        const int sw = blockIdx.x;
        const int M     = sw & 1;
        const int vdown = (sw < 2);
        const int sr = startn[0];
        const int sc = M ? (255 - startn[1]) : startn[1];
        const float* __restrict__ PRu = M ? PRm : PR;
        const int pInc = vdown ? (M ? 5 : 7) : (M ? 0 : 2);
        const int pStr = vdown ? 6 : 1;
        const int pDec = vdown ? (M ? 7 : 5) : (M ? 2 : 0);
        const float* __restrict__ cInP = costP + (pInc << 16);
        const float* __restrict__ cStP = costP + (pStr << 16);
        const float* __restrict__ cDeP = costP + (pDec << 16);
        float* __restrict__ O = distQ + (sw << 16);
        const int iStart = vdown ? sr : (255 - sr);

        const float4 BIG4 = make_float4(BIGV, BIGV, BIGV, BIGV);

        float4 sv = BIG4;
        {
            int kk = sc - (l << 2);
            if (kk == 0) sv.x = 0.0f;
            if (kk == 1) sv.y = 0.0f;
            if (kk == 2) sv.z = 0.0f;
            if (kk == 3) sv.w = 0.0f;
        }

#define ROW_OF(ii)  (vdown ? ((ii) > 255 ? 255 : (ii)) : (255 - ((ii) > 255 ? 255 : (ii))))
#define ROWP_OF(ii) (vdown ? (((ii) - 1) < 0 ? 0 : (((ii) - 1) > 255 ? 255 : ((ii) - 1))) \
                           : (255 - (((ii) - 1) < 0 ? 0 : (((ii) - 1) > 255 ? 255 : ((ii) - 1)))))

        float4 bPR[PIPE], bI[PIPE], bS[PIPE], bD[PIPE];
#pragma unroll
        for (int k = 0; k < PIPE; ++k) {
            int rP = ROW_OF(k), rC = ROWP_OF(k);
            bPR[k] = *(const float4*)&PRu[(rP << 8) + (l << 2)];
            bI[k]  = ld4m(cInP, rC, l, M);
            bS[k]  = ld4m(cStP, rC, l, M);
            bD[k]  = ld4m(cDeP, rC, l, M);
        }

        float4 Dp = BIG4;
        for (int ib = 0; ib < 256; ib += PIPE) {
#pragma unroll
            for (int k = 0; k < PIPE; ++k) {
                const int i = ib + k;
                const int r = vdown ? i : 255 - i;
                float4 PR_c = bPR[k], cI_c = bI[k], cS_c = bS[k], cD_c = bD[k];

                float tS0 = Dp.x + cS_c.x, tS1 = Dp.y + cS_c.y,
                      tS2 = Dp.z + cS_c.z, tS3 = Dp.w + cS_c.w;
                float tI0 = Dp.x + cI_c.x, tI1 = Dp.y + cI_c.y,
                      tI2 = Dp.z + cI_c.z, tI3 = Dp.w + cI_c.w;
                float tD0 = Dp.x + cD_c.x, tD1 = Dp.y + cD_c.y,
                      tD2 = Dp.z + cD_c.z, tD3 = Dp.w + cD_c.w;
                float tIm = dpp_mv<0x138, 0xF>(tI3);   // wave_shr1
                float tDn = dpp_mv<0x130, 0xF>(tD0);   // wave_shl1
                float4 cand;
                cand.x = fminf(tS0, fminf(tIm, tD1));
                cand.y = fminf(tS1, fminf(tI0, tD2));
                cand.z = fminf(tS2, fminf(tI1, tD3));
                cand.w = fminf(tS3, fminf(tI2, tDn));
                if (i == iStart) {
                    cand.x = fminf(cand.x, sv.x);
                    cand.y = fminf(cand.y, sv.y);
                    cand.z = fminf(cand.z, sv.z);
                    cand.w = fminf(cand.w, sv.w);
                }
                float z0 = cand.x - PR_c.x;
                float z1 = fminf(cand.y - PR_c.y, z0);
                float z2 = fminf(cand.z - PR_c.z, z1);
                float z3 = fminf(cand.w - PR_c.w, z2);
                float w  = wave_prefmin(z3);
                float e  = dpp_mv<0x138, 0xF>(w);      // exclusive prefix
                float4 D;
                D.x = PR_c.x + fminf(z0, e);
                D.y = PR_c.y + fminf(z1, e);
                D.z = PR_c.z + fminf(z2, e);
                D.w = PR_c.w + fminf(z3, e);

                *(float4*)&O[(r << 8) + (l << 2)] = D;
                Dp = D;

                {
                    const int jn = i + PIPE;
                    int rP = ROW_OF(jn), rC = ROWP_OF(jn);
                    bPR[k] = *(const float4*)&PRu[(rP << 8) + (l << 2)];
                    bI[k]  = ld4m(cInP, rC, l, M);
                    bS[k]  = ld4m(cStP, rC, l, M);
                    bD[k]  = ld4m(cDeP, rC, l, M);
                }
            }
        }
#undef ROW_OF
#undef ROWP_OF
        return;
    }

    // ================= HEURISTIC PATH (k_pixel minus cost/norm work) =======
    __shared__ float  stage[CHUNK * SP];
    __shared__ float4 w1L[Cd * 8];
    __shared__ float  endfL[64];
    __shared__ float  vendL[64];
    __shared__ float  vendS;

    const int t  = threadIdx.x;
    const int b  = blockIdx.x - 4;
    const int r0 = (b >> 4) * TILE;
    const int c0 = (b & 15) * TILE;

    for (int i = t; i < Cd * 8; i += 256) w1L[i] = ((const float4*)w1)[i];
    const int er = endn[0], ec = endn[1];
    if (t < 64) {
        endfL[t] = feat[(er * Wd + ec) * Cd + t];
        float s1 = 0.0f, s2 = 0.0f;
#pragma unroll
        for (int dr = -1; dr <= 1; ++dr)
#pragma unroll
            for (int dc = -1; dc <= 1; ++dc) {
                int gr = er + dr, gc = ec + dc;
                if ((unsigned)gr < Hd && (unsigned)gc < Wd) {
                    float x = feat[((gr << 8) + gc) * Cd + 64 + t];
                    s1 += x; s2 = fmaf(x, x, s2);
                }
            }
        float m = s1 * (1.0f / 9.0f);
        vendL[t] = s2 * (1.0f / 9.0f) - m * m;
    }

    const int lr = t >> 4, lc = t & 15;
    const int r = r0 + lr, c = c0 + lc;
    const int px0 = (lr + 1) * HPX + (lc + 1);

    float4 hv[8];
#pragma unroll
    for (int j = 0; j < 8; ++j) hv[j] = make_float4(0.f, 0.f, 0.f, 0.f);
    float gm_acc = 0.0f, var_acc = 0.0f, abs_acc = 0.0f;

    for (int ch0 = 0; ch0 < Cd; ch0 += CHUNK) {
        __syncthreads();
        for (int i = t; i < PXN * 8; i += 256) {
            int px = i >> 3, f4 = i & 7;
            int pr = px / HPX;
            int pc = px - pr * HPX;
            int gr = r0 - 1 + pr, gc = c0 - 1 + pc;
            float4 v = make_float4(0.f, 0.f, 0.f, 0.f);
            if ((unsigned)gr < Hd && (unsigned)gc < Wd) {
                v = *reinterpret_cast<const float4*>(
                        &feat[(((gr << 8) + gc) * Cd) + ch0 + (f4 << 2)]);
            }
            int chb = f4 << 2;
            stage[(chb + 0) * SP + px] = v.x;
            stage[(chb + 1) * SP + px] = v.y;
            stage[(chb + 2) * SP + px] = v.z;
            stage[(chb + 3) * SP + px] = v.w;
        }
        __syncthreads();
        const bool is_hf = (ch0 >= 64);
        for (int ch = 0; ch < CHUNK; ++ch) {
            const float* pl = stage + ch * SP + px0;
            float x  = pl[0];
            float n0 = pl[-HPX - 1], n1 = pl[-HPX], n2 = pl[-HPX + 1];
            float n3 = pl[-1],                      n4 = pl[1];
            float n5 = pl[HPX - 1],  n6 = pl[HPX],  n7 = pl[HPX + 1];

            float gx = (n2 + 2.f * n4 + n7) - (n0 + 2.f * n3 + n5);
            float gy = (n5 + 2.f * n6 + n7) - (n0 + 2.f * n1 + n2);
            gm_acc += sqrtf(gx * gx + gy * gy);

            if (is_hf) {
                float s1 = x + n0 + n1 + n2 + n3 + n4 + n5 + n6 + n7;
                float s2 = x*x + n0*n0 + n1*n1 + n2*n2 + n3*n3 + n4*n4
                         + n5*n5 + n6*n6 + n7*n7;
                float m = s1 * (1.0f / 9.0f);
                var_acc += s2 * (1.0f / 9.0f) - m * m;
            } else {
                float dlf = x - endfL[ch0 + ch];
                abs_acc = fmaf(dlf, dlf, abs_acc);
            }

            const float4* __restrict__ wr4 = &w1L[(ch0 + ch) << 3];
#pragma unroll
            for (int j4 = 0; j4 < 8; ++j4) {
                float4 wv = wr4[j4];
                hv[j4].x = fmaf(x, wv.x, hv[j4].x);
                hv[j4].y = fmaf(x, wv.y, hv[j4].y);
                hv[j4].z = fmaf(x, wv.z, hv[j4].z);
                hv[j4].w = fmaf(x, wv.w, hv[j4].w);
            }
        }
    }
    __syncthreads();

    if (t < 64) {
        float v = vendL[t];
#pragma unroll
        for (int o = 32; o > 0; o >>= 1) v += __shfl_down(v, o, 64);
        if (t == 0) vendS = v;
    }
    __syncthreads();
    const float vend = vendS;

    const int p = (r << 8) + c;
    float geo  = gm_acc * (1.0f / 128.0f);
    float absp = sqrtf(abs_acc);
    float o = b2[0];
#pragma unroll
    for (int j4 = 0; j4 < 8; ++j4) {
#pragma unroll
        for (int cc = 0; cc < 4; ++cc) {
            int j = (j4 << 2) + cc;
            float hj = fmaxf(((const float*)&hv[j4])[cc] + b1[j], 0.0f);
            o = fmaf(hj, w2[j], o);
        }
    }
    float omg = 1.0f / (1.0f + expf(-o));
    float dS = softplus_f(dlt[0]);
    float gS = softplus_f(gmm[0]);
    float bS = softplus_f(bta[0]);
    float heur = dS * geo + omg * gS * (vend - var_acc)
               + (1.0f - omg) * bS * absp;
    out[p * 10] = fmaxf(heur, 0.0f);
}

// ---------------------------------------------------------------------------
// Kernel 4: merge the 4 quadrant planes (un-mirroring planes 1,3) -> out ch 9
// ---------------------------------------------------------------------------
__global__ __launch_bounds__(256) void k_merge(
    const float* __restrict__ distQ, float* __restrict__ out)
{
    int p  = blockIdx.x * 256 + threadIdx.x;
    int pm = (p & ~255) + (255 - (p & 255));
    float v = fminf(fminf(distQ[p],           distQ[(2 << 16) + p]),
                    fminf(distQ[(1 << 16) + pm], distQ[(3 << 16) + pm]));
    out[p * 10 + 9] = fminf(v, BIGV);
}

// ---------------------------------------------------------------------------
extern "C" void kernel_launch(void* const* d_in, const int* in_sizes, int n_in,
                              void* d_out, int out_size, void* d_ws, size_t ws_size,
                              hipStream_t stream)
{
    const float* feat  = (const float*)d_in[0];
    const float* dlt   = (const float*)d_in[1];
    const float* gmm   = (const float*)d_in[2];
    const float* bta   = (const float*)d_in[3];
    const float* w1    = (const float*)d_in[4];
    const float* b1    = (const float*)d_in[5];
    const float* w2    = (const float*)d_in[6];
    const float* b2    = (const float*)d_in[7];
    const int*   startn= (const int*)d_in[8];
    const int*   endn  = (const int*)d_in[9];
    float* out = (float*)d_out;
    float* ws  = (float*)d_ws;

    float* costP = ws;                   // 8 planes
    float* PR    = ws + 8  * 65536;
    float* PRm   = ws + 9  * 65536;
    float* distQ = ws + 10 * 65536;      // 4 quadrant planes

    dim3 g16(16, 16);
    k_cost<<<g16, 256, 0, stream>>>(feat, out, costP);
    k_scan<<<256, 64, 0, stream>>>(costP, PR, PRm);
    k_main<<<260, 256, 0, stream>>>(feat, w1, b1, w2, b2, dlt, gmm, bta, endn,
                                    costP, PR, PRm, startn, out, distQ);
    k_merge<<<256, 256, 0, stream>>>(distQ, out);
}